// Round 2
// baseline (482.871 us; speedup 1.0000x reference)
//
#include <hip/hip_runtime.h>
#include <hip/hip_bf16.h>
#include <stdint.h>

// Problem constants (fixed by the reference).
#define B_SZ 16384
#define K_SZ 5
#define H_SZ 512
#define E_SZ 512

typedef _Float16 f16;
typedef _Float16 f16x8 __attribute__((ext_vector_type(8)));
typedef float    f32x4 __attribute__((ext_vector_type(4)));

// ---------------------------------------------------------------------------
// async global->LDS, 16B per lane (gfx950). LDS dest must be wave-uniform
// base + lane*16 -- our staging index maps lane l -> lds byte (base + l*16).
__device__ __forceinline__ void gload_lds16(const void* g, void* l) {
  __builtin_amdgcn_global_load_lds(
      (const __attribute__((address_space(1))) unsigned int*)g,
      (__attribute__((address_space(3))) unsigned int*)l, 16, 0, 0);
}

// ---------------------------------------------------------------------------
// fp32 -> fp16 conversion, 8 elems/thread, vectorized.
__global__ __launch_bounds__(256) void cvt_kernel(const float* __restrict__ src,
                                                  f16* __restrict__ dst, int n8) {
  int i = blockIdx.x * 256 + threadIdx.x;
  if (i >= n8) return;
  size_t o = (size_t)i * 8;
  float4 a = *(const float4*)(src + o);
  float4 b = *(const float4*)(src + o + 4);
  union { f16 h[8]; uint4 u; } u;
  u.h[0] = (f16)a.x; u.h[1] = (f16)a.y; u.h[2] = (f16)a.z; u.h[3] = (f16)a.w;
  u.h[4] = (f16)b.x; u.h[5] = (f16)b.y; u.h[6] = (f16)b.z; u.h[7] = (f16)b.w;
  *(uint4*)(dst + o) = u.u;
}

// ---------------------------------------------------------------------------
// Y[m,n] (f16, pitch ldY) = sum_k A[m,k] * W[n,k].   N = K = 512 fixed.
// W: f16 row-major [512 x 512] (row = output col n) == Wa / Ua layout as given.
// A: f16 (pitch ldA) staged via global_load_lds, or f32 converted in-register.
// 128x128 tile, BK=32, 256 threads = 4 waves (2x2), wave tile 64x64 = 4x4
// frags of 16x16x32 f16 MFMA (m97-structure: single LDS buffer, 2 barriers).
template <bool A_F32>
__global__ __launch_bounds__(256)
void gemm_bt(const void* __restrict__ Aop, const f16* __restrict__ W,
             f16* __restrict__ Y, int ldA, int ldY) {
  __shared__ f16 As[128 * 32];
  __shared__ f16 Bs[128 * 32];
  const int t = threadIdx.x;
  const int l = t & 63, wid = t >> 6;
  const int wm = wid >> 1, wn = wid & 1;
  const int tn = blockIdx.x & 3;          // N=512 -> 4 col tiles
  const size_t m0 = (size_t)(blockIdx.x >> 2) * 128;
  const int n0 = tn * 128;
  const int lrow = l & 15;                // fragment row/col within 16
  const int lk = (l >> 4) * 8;            // fragment k-offset (8 f16)

  f32x4 acc[4][4] = {};

  for (int k0 = 0; k0 < 512; k0 += 32) {
    // ---- stage B tile (f16 always): 128 rows x 64B
    #pragma unroll
    for (int p = 0; p < 2; ++p) {
      int c = p * 256 + t;                // 16B chunk id, 0..511
      int row = c >> 2, seg = c & 3;
      gload_lds16(W + (size_t)(n0 + row) * 512 + k0 + seg * 8,
                  (char*)Bs + c * 16);
    }
    // ---- stage A tile
    if constexpr (!A_F32) {
      const f16* A = (const f16*)Aop;
      #pragma unroll
      for (int p = 0; p < 2; ++p) {
        int c = p * 256 + t;
        int row = c >> 2, seg = c & 3;
        gload_lds16(A + (m0 + row) * (size_t)ldA + k0 + seg * 8,
                    (char*)As + c * 16);
      }
    } else {
      const float* A = (const float*)Aop;
      #pragma unroll
      for (int p = 0; p < 4; ++p) {
        int c = p * 256 + t;              // float4 chunk id, 0..1023
        int row = c >> 3, seg = c & 7;
        const float4 v =
            *(const float4*)(A + (m0 + row) * (size_t)ldA + k0 + seg * 4);
        union { f16 h[4]; uint2 u; } cv;
        cv.h[0] = (f16)v.x; cv.h[1] = (f16)v.y;
        cv.h[2] = (f16)v.z; cv.h[3] = (f16)v.w;
        *(uint2*)((char*)As + row * 64 + seg * 8) = cv.u;
      }
    }
    __syncthreads();  // drains vmcnt (global_load_lds) + lgkmcnt (ds_write)

    f16x8 af[4], bf[4];
    #pragma unroll
    for (int mi = 0; mi < 4; ++mi)
      af[mi] = *(const f16x8*)(As + (wm * 64 + mi * 16 + lrow) * 32 + lk);
    #pragma unroll
    for (int ni = 0; ni < 4; ++ni)
      bf[ni] = *(const f16x8*)(Bs + (wn * 64 + ni * 16 + lrow) * 32 + lk);
    #pragma unroll
    for (int mi = 0; mi < 4; ++mi)
      #pragma unroll
      for (int ni = 0; ni < 4; ++ni)
        acc[mi][ni] = __builtin_amdgcn_mfma_f32_16x16x32_f16(
            af[mi], bf[ni], acc[mi][ni], 0, 0, 0);
    __syncthreads();
  }

  // epilogue: C/D layout col = lane&15, row = (lane>>4)*4 + j  [m89-verified]
  #pragma unroll
  for (int mi = 0; mi < 4; ++mi) {
    #pragma unroll
    for (int j = 0; j < 4; ++j) {
      size_t row = m0 + wm * 64 + mi * 16 + ((l >> 4) << 2) + j;
      #pragma unroll
      for (int ni = 0; ni < 4; ++ni) {
        int col = n0 + wn * 64 + ni * 16 + lrow;
        Y[row * (size_t)ldY + col] = (f16)acc[mi][ni][j];
      }
    }
  }
}

// ---------------------------------------------------------------------------
__device__ __forceinline__ float fast_tanh(float x) {
  float e = __expf(-2.f * fabsf(x));      // in (0,1], no overflow
  float r = (1.f - e) / (1.f + e);
  return copysignf(r, x);
}

// shared tail: softmax over K scores + mt accumulation from fp32 topics.
__device__ __forceinline__ void softmax_mt_dev(size_t b, int l, const float* s,
                                               const float* __restrict__ topics,
                                               float* __restrict__ out) {
  float m = s[0];
  #pragma unroll
  for (int k = 1; k < K_SZ; ++k) m = fmaxf(m, s[k]);
  float a[K_SZ], d = 0.f;
  #pragma unroll
  for (int k = 0; k < K_SZ; ++k) { a[k] = __expf(s[k] - m); d += a[k]; }
  float inv = 1.f / d;
  #pragma unroll
  for (int k = 0; k < K_SZ; ++k) a[k] *= inv;

  float acc0[4] = {}, acc1[4] = {};
  #pragma unroll
  for (int k = 0; k < K_SZ; ++k) {
    const float* tp = topics + (b * K_SZ + k) * E_SZ + l * 8;
    float4 t0 = *(const float4*)tp;
    float4 t1 = *(const float4*)(tp + 4);
    acc0[0] += a[k] * t0.x; acc0[1] += a[k] * t0.y;
    acc0[2] += a[k] * t0.z; acc0[3] += a[k] * t0.w;
    acc1[0] += a[k] * t1.x; acc1[1] += a[k] * t1.y;
    acc1[2] += a[k] * t1.z; acc1[3] += a[k] * t1.w;
  }
  float* mo = out + b * E_SZ + l * 8;
  *(float4*)mo       = make_float4(acc0[0], acc0[1], acc0[2], acc0[3]);
  *(float4*)(mo + 4) = make_float4(acc1[0], acc1[1], acc1[2], acc1[3]);
  if (l < K_SZ) {
    float av = (l == 0) ? a[0] : (l == 1) ? a[1] : (l == 2) ? a[2]
               : (l == 3) ? a[3] : a[4];
    out[(size_t)B_SZ * E_SZ + b * K_SZ + l] = av;
  }
}

// fast path: full pk [B*K, 512] materialized. One wave per b-row.
__global__ __launch_bounds__(256)
void finalize_full(const f16* __restrict__ qall, const f16* __restrict__ pk,
                   const float* __restrict__ topics, const float* __restrict__ cov,
                   const float* __restrict__ va_w, const float* __restrict__ va_b,
                   float* __restrict__ out) {
  const int wid = threadIdx.x >> 6, l = threadIdx.x & 63;
  const size_t b = (size_t)blockIdx.x * 4 + wid;
  const float vb = va_b[0];
  float va[8];
  *(float4*)(va)     = *(const float4*)(va_w + l * 8);
  *(float4*)(va + 4) = *(const float4*)(va_w + l * 8 + 4);

  float s[K_SZ];
  #pragma unroll
  for (int k = 0; k < K_SZ; ++k) {
    const size_t r = (b * K_SZ + k) * 512 + l * 8;
    f16x8 qv = *(const f16x8*)(qall + r);
    f16x8 pv = *(const f16x8*)(pk + r);
    float part = 0.f;
    #pragma unroll
    for (int j = 0; j < 8; ++j)
      part += va[j] * fast_tanh((float)qv[j] + (float)pv[j]);
    #pragma unroll
    for (int off = 32; off > 0; off >>= 1) part += __shfl_xor(part, off);
    s[k] = (part + vb) * cov[b * K_SZ + k];
  }
  softmax_mt_dev(b, l, s, topics, out);
}

// sliced path pieces (used only if ws is too small for full pk).
__global__ __launch_bounds__(256)
void score_one(const f16* __restrict__ qk, const f16* __restrict__ pks,
               const float* __restrict__ cov, const float* __restrict__ va_w,
               const float* __restrict__ va_b, float* __restrict__ scores, int k) {
  const int wid = threadIdx.x >> 6, l = threadIdx.x & 63;
  const size_t b = (size_t)blockIdx.x * 4 + wid;
  float va[8];
  *(float4*)(va)     = *(const float4*)(va_w + l * 8);
  *(float4*)(va + 4) = *(const float4*)(va_w + l * 8 + 4);
  f16x8 qv = *(const f16x8*)(qk + b * (K_SZ * 512) + l * 8);
  f16x8 pv = *(const f16x8*)(pks + b * 512 + l * 8);
  float part = 0.f;
  #pragma unroll
  for (int j = 0; j < 8; ++j)
    part += va[j] * fast_tanh((float)qv[j] + (float)pv[j]);
  #pragma unroll
  for (int off = 32; off > 0; off >>= 1) part += __shfl_xor(part, off);
  if (l == 0)
    scores[b * K_SZ + k] = (part + va_b[0]) * cov[b * K_SZ + k];
}

__global__ __launch_bounds__(256)
void softmax_mt_kernel(const float* __restrict__ scores,
                       const float* __restrict__ topics, float* __restrict__ out) {
  const int wid = threadIdx.x >> 6, l = threadIdx.x & 63;
  const size_t b = (size_t)blockIdx.x * 4 + wid;
  float s[K_SZ];
  #pragma unroll
  for (int k = 0; k < K_SZ; ++k) s[k] = scores[b * K_SZ + k];
  softmax_mt_dev(b, l, s, topics, out);
}

// ---------------------------------------------------------------------------
extern "C" void kernel_launch(void* const* d_in, const int* in_sizes, int n_in,
                              void* d_out, int out_size, void* d_ws, size_t ws_size,
                              hipStream_t stream) {
  const float* query  = (const float*)d_in[0];
  const float* topics = (const float*)d_in[1];
  const float* cov    = (const float*)d_in[2];
  const float* Ua     = (const float*)d_in[3];
  const float* Wa     = (const float*)d_in[4];
  const float* va_w   = (const float*)d_in[5];
  const float* va_b   = (const float*)d_in[6];
  float* out = (float*)d_out;

  char* ws = (char*)d_ws;
  size_t off = 0;
  auto alloc = [&](size_t bytes) -> char* {
    char* p = ws + off;
    off += (bytes + 255) & ~(size_t)255;
    return p;
  };
  f16* q0h  = (f16*)alloc((size_t)B_SZ * H_SZ * 2);          // 16.8 MB
  f16* qall = (f16*)alloc((size_t)B_SZ * K_SZ * H_SZ * 2);   // 83.9 MB  (q1..q5)
  f16* Wa_h = (f16*)alloc((size_t)H_SZ * H_SZ * 2);
  f16* Ua_h = (f16*)alloc((size_t)H_SZ * E_SZ * 2);
  size_t base = off;
  const size_t pk_full_b  = (size_t)B_SZ * K_SZ * H_SZ * 2;  // 83.9 MB
  const size_t pk_slice_b = (size_t)B_SZ * H_SZ * 2;         // 16.8 MB
  const size_t scores_b   = (size_t)B_SZ * K_SZ * 4;
  bool fast = (base + pk_full_b) <= ws_size;

  // converts
  cvt_kernel<<<(B_SZ * H_SZ / 8 + 255) / 256, 256, 0, stream>>>(query, q0h,
                                                                B_SZ * H_SZ / 8);
  cvt_kernel<<<(H_SZ * H_SZ / 8 + 255) / 256, 256, 0, stream>>>(Wa, Wa_h,
                                                                H_SZ * H_SZ / 8);
  cvt_kernel<<<(H_SZ * E_SZ / 8 + 255) / 256, 256, 0, stream>>>(Ua, Ua_h,
                                                                H_SZ * E_SZ / 8);
  // chain: qall[:,i,:] = q_{i+1}
  gemm_bt<false><<<(B_SZ / 128) * 4, 256, 0, stream>>>(q0h, Wa_h, qall,
                                                       H_SZ, K_SZ * H_SZ);
  for (int i = 1; i < K_SZ; ++i)
    gemm_bt<false><<<(B_SZ / 128) * 4, 256, 0, stream>>>(
        qall + (size_t)(i - 1) * H_SZ, Wa_h, qall + (size_t)i * H_SZ,
        K_SZ * H_SZ, K_SZ * H_SZ);

  if (fast) {
    f16* pk = (f16*)(ws + base);
    gemm_bt<true><<<(B_SZ * K_SZ / 128) * 4, 256, 0, stream>>>(
        topics, Ua_h, pk, E_SZ, H_SZ);
    finalize_full<<<B_SZ / 4, 256, 0, stream>>>(qall, pk, topics, cov, va_w,
                                                va_b, out);
  } else {
    f16* pks = (f16*)(ws + base);
    float* scores = (float*)(ws + base + ((pk_slice_b + 255) & ~(size_t)255));
    (void)scores_b;
    for (int k = 0; k < K_SZ; ++k) {
      gemm_bt<true><<<(B_SZ / 128) * 4, 256, 0, stream>>>(
          topics + (size_t)k * E_SZ, Ua_h, pks, K_SZ * E_SZ, H_SZ);
      score_one<<<B_SZ / 4, 256, 0, stream>>>(qall + (size_t)k * H_SZ, pks,
                                              cov, va_w, va_b, scores, k);
    }
    softmax_mt_kernel<<<B_SZ / 4, 256, 0, stream>>>(scores, topics, out);
  }
}